// Round 1
// baseline (741.917 us; speedup 1.0000x reference)
//
#include <hip/hip_runtime.h>
#include <math.h>

// Problem constants
#define BB 32
#define NN 1024
#define DD 768
#define KK 512
#define MM (BB * NN)  // 32768 rows for GEMM1

// ---------------------------------------------------------------------------
// Kernel 1: c_sq[k] = sum_d codebook[k][d]^2   (one block per k)
// ---------------------------------------------------------------------------
__global__ __launch_bounds__(256) void csq_kernel(const float* __restrict__ cb,
                                                  float* __restrict__ csq) {
    int k = blockIdx.x;
    const float* row = cb + k * DD;
    float s = 0.f;
    for (int d = threadIdx.x; d < DD; d += 256) {
        float v = row[d];
        s += v * v;
    }
    #pragma unroll
    for (int off = 32; off > 0; off >>= 1) s += __shfl_down(s, off);
    __shared__ float sm[4];
    int lane = threadIdx.x & 63, wid = threadIdx.x >> 6;
    if (lane == 0) sm[wid] = s;
    __syncthreads();
    if (threadIdx.x == 0) csq[k] = sm[0] + sm[1] + sm[2] + sm[3];
}

// ---------------------------------------------------------------------------
// Kernel 2: logits L[m][k] = 2 * dot(X[m], Cb[k]) - csq[k]
// Tiled fp32 GEMM (NT): block tile 128x128, k-chunk 8, 8x8 per thread.
// ---------------------------------------------------------------------------
__global__ __launch_bounds__(256) void gemm1_kernel(const float* __restrict__ X,
                                                    const float* __restrict__ Cb,
                                                    const float* __restrict__ csq,
                                                    float* __restrict__ L) {
    __shared__ float As[8][128];  // [d-chunk][m]
    __shared__ float Bs[8][128];  // [d-chunk][k]

    const int m0 = blockIdx.x * 128;
    const int k0 = blockIdx.y * 128;
    const int t  = threadIdx.x;
    const int lr = t >> 1;          // 0..127 : row within tile (load phase)
    const int lc = (t & 1) * 4;     // 0 or 4 : d offset (load phase)
    const int ty = t >> 4;          // 0..15  : row group (compute phase)
    const int tx = t & 15;          // 0..15  : col group (compute phase)

    float acc[8][8];
    #pragma unroll
    for (int i = 0; i < 8; i++)
        #pragma unroll
        for (int j = 0; j < 8; j++) acc[i][j] = 0.f;

    for (int d0 = 0; d0 < DD; d0 += 8) {
        float4 av = *(const float4*)&X[(size_t)(m0 + lr) * DD + d0 + lc];
        float4 bv = *(const float4*)&Cb[(size_t)(k0 + lr) * DD + d0 + lc];
        __syncthreads();
        As[lc + 0][lr] = av.x; As[lc + 1][lr] = av.y;
        As[lc + 2][lr] = av.z; As[lc + 3][lr] = av.w;
        Bs[lc + 0][lr] = bv.x; Bs[lc + 1][lr] = bv.y;
        Bs[lc + 2][lr] = bv.z; Bs[lc + 3][lr] = bv.w;
        __syncthreads();
        #pragma unroll
        for (int dd = 0; dd < 8; dd++) {
            float4 a0 = *(const float4*)&As[dd][ty * 8];
            float4 a1 = *(const float4*)&As[dd][ty * 8 + 4];
            float4 b0 = *(const float4*)&Bs[dd][tx * 4];
            float4 b1 = *(const float4*)&Bs[dd][64 + tx * 4];
            float a[8] = {a0.x, a0.y, a0.z, a0.w, a1.x, a1.y, a1.z, a1.w};
            float b[8] = {b0.x, b0.y, b0.z, b0.w, b1.x, b1.y, b1.z, b1.w};
            #pragma unroll
            for (int i = 0; i < 8; i++)
                #pragma unroll
                for (int j = 0; j < 8; j++) acc[i][j] += a[i] * b[j];
        }
    }

    // epilogue: 2*acc - csq[k]
    float cs[8];
    #pragma unroll
    for (int j = 0; j < 4; j++) {
        cs[j]     = csq[k0 + tx * 4 + j];
        cs[j + 4] = csq[k0 + 64 + tx * 4 + j];
    }
    #pragma unroll
    for (int i = 0; i < 8; i++) {
        int m = m0 + ty * 8 + i;
        float4 o0, o1;
        o0.x = 2.f * acc[i][0] - cs[0];
        o0.y = 2.f * acc[i][1] - cs[1];
        o0.z = 2.f * acc[i][2] - cs[2];
        o0.w = 2.f * acc[i][3] - cs[3];
        o1.x = 2.f * acc[i][4] - cs[4];
        o1.y = 2.f * acc[i][5] - cs[5];
        o1.z = 2.f * acc[i][6] - cs[6];
        o1.w = 2.f * acc[i][7] - cs[7];
        *(float4*)&L[(size_t)m * KK + k0 + tx * 4]      = o0;
        *(float4*)&L[(size_t)m * KK + k0 + 64 + tx * 4] = o1;
    }
}

// ---------------------------------------------------------------------------
// Kernel 3: in-place row softmax over K=512 (one block of 256 per row)
// ---------------------------------------------------------------------------
__global__ __launch_bounds__(256) void softmax_kernel(float* __restrict__ L) {
    const size_t r = blockIdx.x;
    float* row = L + r * KK;
    const int t = threadIdx.x;
    float2 v = *(float2*)&row[t * 2];

    float m = fmaxf(v.x, v.y);
    #pragma unroll
    for (int off = 32; off > 0; off >>= 1) m = fmaxf(m, __shfl_down(m, off));
    __shared__ float sm[4];
    __shared__ float ss[4];
    int lane = t & 63, wid = t >> 6;
    if (lane == 0) sm[wid] = m;
    __syncthreads();
    m = fmaxf(fmaxf(sm[0], sm[1]), fmaxf(sm[2], sm[3]));

    float e0 = __expf(v.x - m);
    float e1 = __expf(v.y - m);
    float s = e0 + e1;
    #pragma unroll
    for (int off = 32; off > 0; off >>= 1) s += __shfl_down(s, off);
    if (lane == 0) ss[wid] = s;
    __syncthreads();
    s = ss[0] + ss[1] + ss[2] + ss[3];
    float inv = 1.f / s;
    float2 o;
    o.x = e0 * inv;
    o.y = e1 * inv;
    *(float2*)&row[t * 2] = o;
}

// ---------------------------------------------------------------------------
// Kernel 4: out[b][k][d] = sum_n S[b][n][k] * X[b][n][d]
// Batched TN GEMM: block tile 128(k) x 128(d), n-chunk 8, 8x8 per thread.
// ---------------------------------------------------------------------------
__global__ __launch_bounds__(256) void gemm2_kernel(const float* __restrict__ S,
                                                    const float* __restrict__ X,
                                                    float* __restrict__ out) {
    __shared__ float Ss[8][128];  // [n-chunk][k]
    __shared__ float Xs[8][128];  // [n-chunk][d]

    const int b  = blockIdx.z;
    const int d0 = blockIdx.x * 128;
    const int k0 = blockIdx.y * 128;
    const float* Sb = S + (size_t)b * NN * KK;
    const float* Xb = X + (size_t)b * NN * DD;

    const int t   = threadIdx.x;
    const int row = t >> 5;          // 0..7
    const int col = (t & 31) * 4;    // 0..124
    const int ty  = t >> 4;          // 0..15 : k-row group
    const int tx  = t & 15;          // 0..15 : d-col group

    float acc[8][8];
    #pragma unroll
    for (int i = 0; i < 8; i++)
        #pragma unroll
        for (int j = 0; j < 8; j++) acc[i][j] = 0.f;

    for (int n0 = 0; n0 < NN; n0 += 8) {
        float4 sv = *(const float4*)&Sb[(size_t)(n0 + row) * KK + k0 + col];
        float4 xv = *(const float4*)&Xb[(size_t)(n0 + row) * DD + d0 + col];
        __syncthreads();
        *(float4*)&Ss[row][col] = sv;
        *(float4*)&Xs[row][col] = xv;
        __syncthreads();
        #pragma unroll
        for (int dd = 0; dd < 8; dd++) {
            float4 a0 = *(const float4*)&Ss[dd][ty * 8];
            float4 a1 = *(const float4*)&Ss[dd][ty * 8 + 4];
            float4 b0 = *(const float4*)&Xs[dd][tx * 4];
            float4 b1 = *(const float4*)&Xs[dd][64 + tx * 4];
            float a[8] = {a0.x, a0.y, a0.z, a0.w, a1.x, a1.y, a1.z, a1.w};
            float bb[8] = {b0.x, b0.y, b0.z, b0.w, b1.x, b1.y, b1.z, b1.w};
            #pragma unroll
            for (int i = 0; i < 8; i++)
                #pragma unroll
                for (int j = 0; j < 8; j++) acc[i][j] += a[i] * bb[j];
        }
    }

    #pragma unroll
    for (int i = 0; i < 8; i++) {
        int k = k0 + ty * 8 + i;
        float4 o0, o1;
        o0.x = acc[i][0]; o0.y = acc[i][1]; o0.z = acc[i][2]; o0.w = acc[i][3];
        o1.x = acc[i][4]; o1.y = acc[i][5]; o1.z = acc[i][6]; o1.w = acc[i][7];
        *(float4*)&out[((size_t)b * KK + k) * DD + d0 + tx * 4]      = o0;
        *(float4*)&out[((size_t)b * KK + k) * DD + d0 + 64 + tx * 4] = o1;
    }
}

// ---------------------------------------------------------------------------
extern "C" void kernel_launch(void* const* d_in, const int* in_sizes, int n_in,
                              void* d_out, int out_size, void* d_ws, size_t ws_size,
                              hipStream_t stream) {
    const float* x  = (const float*)d_in[0];   // [B,N,D]
    const float* cb = (const float*)d_in[1];   // [K,D]
    float* out = (float*)d_out;                // [B,K,D]

    float* csq = (float*)d_ws;                 // K floats (pad to 1024)
    float* L   = (float*)d_ws + 1024;          // [M,K] = 64 MB soft-assignments

    csq_kernel<<<KK, 256, 0, stream>>>(cb, csq);
    gemm1_kernel<<<dim3(MM / 128, KK / 128), 256, 0, stream>>>(x, cb, csq, L);
    softmax_kernel<<<MM, 256, 0, stream>>>(L);
    gemm2_kernel<<<dim3(DD / 128, KK / 128, BB), 256, 0, stream>>>(L, x, out);
}

// Round 2
// 341.843 us; speedup vs baseline: 2.1703x; 2.1703x over previous
//
#include <hip/hip_runtime.h>
#include <math.h>

// Problem constants
#define BB 32
#define NN 1024
#define DD 768
#define KK 512
#define MM (BB * NN)  // 32768 token rows

typedef _Float16 half8 __attribute__((ext_vector_type(8)));
typedef _Float16 half2v __attribute__((ext_vector_type(2)));
typedef float floatx4 __attribute__((ext_vector_type(4)));

// ---------------------------------------------------------------------------
// cast fp32 -> fp16, 8 elements per thread
// ---------------------------------------------------------------------------
__global__ __launch_bounds__(256) void cast_f32_f16(const float* __restrict__ src,
                                                    _Float16* __restrict__ dst,
                                                    int n8) {
    int i = blockIdx.x * 256 + threadIdx.x;
    if (i >= n8) return;
    float4 a = ((const float4*)src)[2 * i];
    float4 b = ((const float4*)src)[2 * i + 1];
    half8 h;
    h[0] = (_Float16)a.x; h[1] = (_Float16)a.y; h[2] = (_Float16)a.z; h[3] = (_Float16)a.w;
    h[4] = (_Float16)b.x; h[5] = (_Float16)b.y; h[6] = (_Float16)b.z; h[7] = (_Float16)b.w;
    ((half8*)dst)[i] = h;
}

// ---------------------------------------------------------------------------
// csq[k] = sum_d codebook[k][d]^2 (fp32 input)
// ---------------------------------------------------------------------------
__global__ __launch_bounds__(256) void csq_kernel(const float* __restrict__ cb,
                                                  float* __restrict__ csq) {
    int k = blockIdx.x;
    const float* row = cb + (size_t)k * DD;
    float s = 0.f;
    for (int d = threadIdx.x; d < DD; d += 256) {
        float v = row[d];
        s += v * v;
    }
    #pragma unroll
    for (int off = 32; off > 0; off >>= 1) s += __shfl_down(s, off);
    __shared__ float sm[4];
    int lane = threadIdx.x & 63, wid = threadIdx.x >> 6;
    if (lane == 0) sm[wid] = s;
    __syncthreads();
    if (threadIdx.x == 0) csq[k] = sm[0] + sm[1] + sm[2] + sm[3];
}

// ---------------------------------------------------------------------------
// GEMM1 (MFMA fp16): L[m][k] = 2*dot(Xh[m,:], Cbh[k,:]) - csq[k]
// 128x128 block tile, 4 waves (2x2), 4x4 MFMA tiles of 16x16x32 per wave.
// ---------------------------------------------------------------------------
__global__ __launch_bounds__(256) void gemm1_mfma(const _Float16* __restrict__ Xh,
                                                  const _Float16* __restrict__ Cbh,
                                                  const float* __restrict__ csq,
                                                  float* __restrict__ L) {
    __shared__ _Float16 As[128][40];  // [m][d-chunk], +8 pad
    __shared__ _Float16 Bs[128][40];  // [k][d-chunk]

    const int m0 = blockIdx.x * 128;
    const int k0 = blockIdx.y * 128;
    const int t = threadIdx.x;
    const int wave = t >> 6;
    const int lane = t & 63;
    const int wm = (wave >> 1) * 64;
    const int wn = (wave & 1) * 64;
    const int l15 = lane & 15;
    const int quad = lane >> 4;

    const int sr = t >> 1;          // 0..127 staging row
    const int sc = (t & 1) * 16;    // 0 or 16 (halfs)

    floatx4 acc[4][4] = {};

    const _Float16* xrow = Xh + (size_t)(m0 + sr) * DD + sc;
    const _Float16* crow = Cbh + (size_t)(k0 + sr) * DD + sc;

    for (int d0 = 0; d0 < DD; d0 += 32) {
        half8 xa = *(const half8*)(xrow + d0);
        half8 xb = *(const half8*)(xrow + d0 + 8);
        half8 ca = *(const half8*)(crow + d0);
        half8 cc = *(const half8*)(crow + d0 + 8);
        __syncthreads();
        *(half8*)&As[sr][sc] = xa;  *(half8*)&As[sr][sc + 8] = xb;
        *(half8*)&Bs[sr][sc] = ca;  *(half8*)&Bs[sr][sc + 8] = cc;
        __syncthreads();
        half8 af[4], bf[4];
        #pragma unroll
        for (int i = 0; i < 4; i++) af[i] = *(half8*)&As[wm + i * 16 + l15][quad * 8];
        #pragma unroll
        for (int i = 0; i < 4; i++) bf[i] = *(half8*)&Bs[wn + i * 16 + l15][quad * 8];
        #pragma unroll
        for (int mi = 0; mi < 4; mi++)
            #pragma unroll
            for (int ni = 0; ni < 4; ni++)
                acc[mi][ni] = __builtin_amdgcn_mfma_f32_16x16x32_f16(af[mi], bf[ni], acc[mi][ni], 0, 0, 0);
    }

    // epilogue: 2*acc - csq[k];  D layout: col=lane&15, row=quad*4+reg
    #pragma unroll
    for (int ni = 0; ni < 4; ni++) {
        float cs = csq[k0 + wn + ni * 16 + l15];
        #pragma unroll
        for (int mi = 0; mi < 4; mi++) {
            int m = m0 + wm + mi * 16 + quad * 4;
            float* Lp = L + (size_t)m * KK + k0 + wn + ni * 16 + l15;
            floatx4 a = acc[mi][ni];
            Lp[0 * KK] = 2.f * a[0] - cs;
            Lp[1 * KK] = 2.f * a[1] - cs;
            Lp[2 * KK] = 2.f * a[2] - cs;
            Lp[3 * KK] = 2.f * a[3] - cs;
        }
    }
}

// ---------------------------------------------------------------------------
// Softmax over K=512 (fp32 in), writes fp16 result in-place at row base.
// Safe: all loads complete before first barrier; stores after last barrier.
// ---------------------------------------------------------------------------
__global__ __launch_bounds__(256) void softmax_kernel(float* __restrict__ L) {
    const size_t r = blockIdx.x;
    float* row = L + r * KK;
    const int t = threadIdx.x;
    float2 v = *(float2*)&row[t * 2];

    float m = fmaxf(v.x, v.y);
    #pragma unroll
    for (int off = 32; off > 0; off >>= 1) m = fmaxf(m, __shfl_down(m, off));
    __shared__ float sm[4];
    __shared__ float ss[4];
    int lane = t & 63, wid = t >> 6;
    if (lane == 0) sm[wid] = m;
    __syncthreads();
    m = fmaxf(fmaxf(sm[0], sm[1]), fmaxf(sm[2], sm[3]));

    float e0 = __expf(v.x - m);
    float e1 = __expf(v.y - m);
    float s = e0 + e1;
    #pragma unroll
    for (int off = 32; off > 0; off >>= 1) s += __shfl_down(s, off);
    if (lane == 0) ss[wid] = s;
    __syncthreads();
    s = ss[0] + ss[1] + ss[2] + ss[3];
    float inv = 1.f / s;
    half2v o;
    o[0] = (_Float16)(e0 * inv);
    o[1] = (_Float16)(e1 * inv);
    *(half2v*)((_Float16*)row + t * 2) = o;  // fp16, row stride 1024 halfs
}

// ---------------------------------------------------------------------------
// Transpose S (fp16, row stride 1024 halfs over M rows of 512) -> St[b][k][n]
// Tile: 64 token-rows x 32 k-cols.
// ---------------------------------------------------------------------------
__global__ __launch_bounds__(256) void transpose_s(const _Float16* __restrict__ S,
                                                   _Float16* __restrict__ St) {
    const int m0 = blockIdx.x * 64;   // global token row
    const int k0 = blockIdx.y * 32;
    __shared__ _Float16 Ls[64][40];
    const int t = threadIdx.x;
    const int r = t >> 2, c8 = (t & 3) * 8;
    *(half8*)&Ls[r][c8] = *(const half8*)&S[(size_t)(m0 + r) * 1024 + k0 + c8];
    __syncthreads();
    const int kr = t >> 3;          // 0..31
    const int nc = (t & 7) * 8;     // 0..56
    const int b = m0 >> 10;
    const int nn = (m0 & 1023) + nc;
    half8 o;
    #pragma unroll
    for (int j = 0; j < 8; j++) o[j] = Ls[nc + j][kr];
    *(half8*)&St[((size_t)b * KK + k0 + kr) * NN + nn] = o;
}

// ---------------------------------------------------------------------------
// Cast+transpose X (fp32 [b][n][d]) -> Xt (fp16 [b][d][n])
// Tile: 64 n-rows x 32 d-cols per batch.
// ---------------------------------------------------------------------------
__global__ __launch_bounds__(256) void transpose_xt(const float* __restrict__ X,
                                                    _Float16* __restrict__ Xt) {
    const int n0 = blockIdx.x * 64;
    const int d0 = blockIdx.y * 32;
    const int b = blockIdx.z;
    __shared__ _Float16 Ls[64][40];
    const int t = threadIdx.x;
    const int r = t >> 2, c8 = (t & 3) * 8;
    const float* src = X + ((size_t)(b << 10) + n0 + r) * DD + d0 + c8;
    float4 f0 = *(const float4*)src;
    float4 f1 = *(const float4*)(src + 4);
    half8 h;
    h[0] = (_Float16)f0.x; h[1] = (_Float16)f0.y; h[2] = (_Float16)f0.z; h[3] = (_Float16)f0.w;
    h[4] = (_Float16)f1.x; h[5] = (_Float16)f1.y; h[6] = (_Float16)f1.z; h[7] = (_Float16)f1.w;
    *(half8*)&Ls[r][c8] = h;
    __syncthreads();
    const int dr = t >> 3;          // 0..31
    const int nc = (t & 7) * 8;     // 0..56
    half8 o;
    #pragma unroll
    for (int j = 0; j < 8; j++) o[j] = Ls[nc + j][dr];
    *(half8*)&Xt[((size_t)b * DD + d0 + dr) * NN + n0 + nc] = o;
}

// ---------------------------------------------------------------------------
// GEMM2 (MFMA fp16): out[b][k][d] = sum_n St[b][k][n] * Xt[b][d][n]
// Same structure as gemm1; contraction = n (1024).
// ---------------------------------------------------------------------------
__global__ __launch_bounds__(256) void gemm2_mfma(const _Float16* __restrict__ St,
                                                  const _Float16* __restrict__ Xt,
                                                  float* __restrict__ out) {
    __shared__ _Float16 As[128][40];  // [k][n-chunk]
    __shared__ _Float16 Bs[128][40];  // [d][n-chunk]

    const int d0 = blockIdx.x * 128;
    const int k0 = blockIdx.y * 128;
    const int b = blockIdx.z;
    const int t = threadIdx.x;
    const int wave = t >> 6;
    const int lane = t & 63;
    const int wm = (wave >> 1) * 64;
    const int wn = (wave & 1) * 64;
    const int l15 = lane & 15;
    const int quad = lane >> 4;

    const int sr = t >> 1;
    const int sc = (t & 1) * 16;

    floatx4 acc[4][4] = {};

    const _Float16* arow = St + ((size_t)b * KK + k0 + sr) * NN + sc;
    const _Float16* brow = Xt + ((size_t)b * DD + d0 + sr) * NN + sc;

    for (int n0 = 0; n0 < NN; n0 += 32) {
        half8 aa = *(const half8*)(arow + n0);
        half8 ab = *(const half8*)(arow + n0 + 8);
        half8 ba = *(const half8*)(brow + n0);
        half8 bb2 = *(const half8*)(brow + n0 + 8);
        __syncthreads();
        *(half8*)&As[sr][sc] = aa;  *(half8*)&As[sr][sc + 8] = ab;
        *(half8*)&Bs[sr][sc] = ba;  *(half8*)&Bs[sr][sc + 8] = bb2;
        __syncthreads();
        half8 af[4], bf[4];
        #pragma unroll
        for (int i = 0; i < 4; i++) af[i] = *(half8*)&As[wm + i * 16 + l15][quad * 8];
        #pragma unroll
        for (int i = 0; i < 4; i++) bf[i] = *(half8*)&Bs[wn + i * 16 + l15][quad * 8];
        #pragma unroll
        for (int mi = 0; mi < 4; mi++)
            #pragma unroll
            for (int ni = 0; ni < 4; ni++)
                acc[mi][ni] = __builtin_amdgcn_mfma_f32_16x16x32_f16(af[mi], bf[ni], acc[mi][ni], 0, 0, 0);
    }

    #pragma unroll
    for (int ni = 0; ni < 4; ni++) {
        #pragma unroll
        for (int mi = 0; mi < 4; mi++) {
            int k = k0 + wm + mi * 16 + quad * 4;
            int d = d0 + wn + ni * 16 + l15;
            float* op = out + ((size_t)b * KK + k) * DD + d;
            floatx4 a = acc[mi][ni];
            op[0 * DD] = a[0];
            op[1 * DD] = a[1];
            op[2 * DD] = a[2];
            op[3 * DD] = a[3];
        }
    }
}

// ---------------------------------------------------------------------------
extern "C" void kernel_launch(void* const* d_in, const int* in_sizes, int n_in,
                              void* d_out, int out_size, void* d_ws, size_t ws_size,
                              hipStream_t stream) {
    const float* x  = (const float*)d_in[0];   // [B,N,D] fp32
    const float* cb = (const float*)d_in[1];   // [K,D] fp32
    float* out = (float*)d_out;                // [B,K,D] fp32

    char* ws = (char*)d_ws;
    float*    csq = (float*)ws;                                   // 4 KB
    _Float16* Xh  = (_Float16*)(ws + 4096);                       // 48 MB (later reused as Xt)
    _Float16* Cbh = (_Float16*)(ws + 4096 + 50331648);            // 768 KB
    float*    L   = (float*)(ws + 4096 + 50331648 + 786432);      // 64 MB (later holds S fp16)
    _Float16* St  = (_Float16*)(ws + 4096 + 50331648 + 786432 + 67108864); // 32 MB
    _Float16* Xt  = Xh;  // region reuse: Xh dead after gemm1

    // Phase 1: casts + csq
    cast_f32_f16<<<(MM * DD / 8 + 255) / 256, 256, 0, stream>>>(x, Xh, MM * DD / 8);
    cast_f32_f16<<<(KK * DD / 8 + 255) / 256, 256, 0, stream>>>(cb, Cbh, KK * DD / 8);
    csq_kernel<<<KK, 256, 0, stream>>>(cb, csq);

    // Phase 2: logits
    gemm1_mfma<<<dim3(MM / 128, KK / 128), 256, 0, stream>>>(Xh, Cbh, csq, L);

    // Phase 3: Xt (reuses Xh region — must come after gemm1)
    transpose_xt<<<dim3(NN / 64, DD / 32, BB), 256, 0, stream>>>(x, Xt);

    // Phase 4: softmax (L fp32 -> S fp16 in-place, row stride 1024 halfs)
    softmax_kernel<<<MM, 256, 0, stream>>>(L);

    // Phase 5: transpose S -> St[b][k][n]
    transpose_s<<<dim3(MM / 64, KK / 32), 256, 0, stream>>>((const _Float16*)L, St);

    // Phase 6: aggregate
    gemm2_mfma<<<dim3(DD / 128, KK / 128, BB), 256, 0, stream>>>(St, Xt, out);
}

// Round 3
// 330.971 us; speedup vs baseline: 2.2416x; 1.0328x over previous
//
#include <hip/hip_runtime.h>
#include <math.h>

// Problem constants
#define BB 32
#define NN 1024
#define DD 768
#define KK 512
#define MM (BB * NN)  // 32768 token rows

typedef _Float16 half8 __attribute__((ext_vector_type(8)));
typedef _Float16 half4 __attribute__((ext_vector_type(4)));
typedef float floatx4 __attribute__((ext_vector_type(4)));

// ---------------------------------------------------------------------------
// cast fp32 -> fp16 (codebook only), 8 elements per thread
// ---------------------------------------------------------------------------
__global__ __launch_bounds__(256) void cast_f32_f16(const float* __restrict__ src,
                                                    _Float16* __restrict__ dst,
                                                    int n8) {
    int i = blockIdx.x * 256 + threadIdx.x;
    if (i >= n8) return;
    float4 a = ((const float4*)src)[2 * i];
    float4 b = ((const float4*)src)[2 * i + 1];
    half8 h;
    h[0] = (_Float16)a.x; h[1] = (_Float16)a.y; h[2] = (_Float16)a.z; h[3] = (_Float16)a.w;
    h[4] = (_Float16)b.x; h[5] = (_Float16)b.y; h[6] = (_Float16)b.z; h[7] = (_Float16)b.w;
    ((half8*)dst)[i] = h;
}

// ---------------------------------------------------------------------------
// csq[k] = sum_d codebook[k][d]^2 (fp32 input)
// ---------------------------------------------------------------------------
__global__ __launch_bounds__(256) void csq_kernel(const float* __restrict__ cb,
                                                  float* __restrict__ csq) {
    int k = blockIdx.x;
    const float* row = cb + (size_t)k * DD;
    float s = 0.f;
    for (int d = threadIdx.x; d < DD; d += 256) {
        float v = row[d];
        s += v * v;
    }
    #pragma unroll
    for (int off = 32; off > 0; off >>= 1) s += __shfl_down(s, off);
    __shared__ float sm[4];
    int lane = threadIdx.x & 63, wid = threadIdx.x >> 6;
    if (lane == 0) sm[wid] = s;
    __syncthreads();
    if (threadIdx.x == 0) csq[k] = sm[0] + sm[1] + sm[2] + sm[3];
}

// ---------------------------------------------------------------------------
// FUSED: logits (MFMA fp16) + softmax (fp32, in-register) + transposed write.
// Block = 4 waves, covers 32 tokens x ALL 512 k. Wave w owns k-slab w*128.
// Acc per wave: 2 m-tiles x 8 k-tiles of 16x16 (64 VGPRs).
// After d-loop (contraction D=768), softmax over k:
//   in-lane (8 k-tiles) -> shfl_xor over l15 (16 lanes, k varies, m fixed)
//   -> LDS across 4 waves. Then exp, scale, write St[b][k][n] fp16.
// ---------------------------------------------------------------------------
__global__ __launch_bounds__(256) void fused_logits_softmax(
    const float* __restrict__ X,        // [M, D] fp32
    const _Float16* __restrict__ Cbh,   // [K, D] fp16
    const float* __restrict__ csq,      // [K]
    _Float16* __restrict__ St)          // [B, K, N] fp16
{
    __shared__ _Float16 Cs[512][40];    // 40 KB codebook d-chunk
    __shared__ _Float16 Xs[32][40];     // 2.5 KB token d-chunk
    __shared__ float redbuf[4][32];     // cross-wave softmax scratch

    const int t = threadIdx.x;
    const int wave = t >> 6;
    const int lane = t & 63;
    const int l15 = lane & 15;
    const int quad = lane >> 4;
    const int gm0 = blockIdx.x * 32;    // global token base
    const int k0w = wave * 128;         // this wave's k-slab

    // csq for this lane's 8 k columns
    float cs[8];
    #pragma unroll
    for (int ki = 0; ki < 8; ki++) cs[ki] = csq[k0w + ki * 16 + l15];

    floatx4 acc[2][8] = {};

    // staging assignments
    const int xrow = t >> 3;            // 0..31
    const int xcol = (t & 7) * 4;       // 0..28
    const float* xsrc = X + (size_t)(gm0 + xrow) * DD + xcol;
    const int crow = t >> 2;            // 0..63 (+64*i)
    const int ccol = (t & 3) * 8;       // 0..24
    const _Float16* csrc = Cbh + (size_t)crow * DD + ccol;

    for (int d0 = 0; d0 < DD; d0 += 32) {
        float4 xv = *(const float4*)(xsrc + d0);
        half8 cv[8];
        #pragma unroll
        for (int i = 0; i < 8; i++)
            cv[i] = *(const half8*)(csrc + (size_t)(i * 64) * DD + d0);
        __syncthreads();
        half4 xh;
        xh[0] = (_Float16)xv.x; xh[1] = (_Float16)xv.y;
        xh[2] = (_Float16)xv.z; xh[3] = (_Float16)xv.w;
        *(half4*)&Xs[xrow][xcol] = xh;
        #pragma unroll
        for (int i = 0; i < 8; i++) *(half8*)&Cs[crow + i * 64][ccol] = cv[i];
        __syncthreads();

        half8 af[2], bf[8];
        af[0] = *(half8*)&Xs[l15][quad * 8];
        af[1] = *(half8*)&Xs[16 + l15][quad * 8];
        #pragma unroll
        for (int ki = 0; ki < 8; ki++)
            bf[ki] = *(half8*)&Cs[k0w + ki * 16 + l15][quad * 8];
        #pragma unroll
        for (int mi = 0; mi < 2; mi++)
            #pragma unroll
            for (int ki = 0; ki < 8; ki++)
                acc[mi][ki] = __builtin_amdgcn_mfma_f32_16x16x32_f16(af[mi], bf[ki], acc[mi][ki], 0, 0, 0);
    }

    // ---- softmax over k=512 ----
    // logit = 2*acc - cs[ki].  C/D layout: k-col = l15 (+16*ki), m-row = quad*4+reg (+16*mi)

    // 1) max
    float pmax[2][4];
    #pragma unroll
    for (int mi = 0; mi < 2; mi++)
        #pragma unroll
        for (int r = 0; r < 4; r++) {
            float m = -1e30f;
            #pragma unroll
            for (int ki = 0; ki < 8; ki++)
                m = fmaxf(m, 2.f * acc[mi][ki][r] - cs[ki]);
            pmax[mi][r] = m;
        }
    #pragma unroll
    for (int off = 1; off < 16; off <<= 1)
        #pragma unroll
        for (int mi = 0; mi < 2; mi++)
            #pragma unroll
            for (int r = 0; r < 4; r++)
                pmax[mi][r] = fmaxf(pmax[mi][r], __shfl_xor(pmax[mi][r], off));
    if (l15 == 0) {
        #pragma unroll
        for (int mi = 0; mi < 2; mi++)
            #pragma unroll
            for (int r = 0; r < 4; r++)
                redbuf[wave][mi * 16 + quad * 4 + r] = pmax[mi][r];
    }
    __syncthreads();
    float gmax[2][4];
    #pragma unroll
    for (int mi = 0; mi < 2; mi++)
        #pragma unroll
        for (int r = 0; r < 4; r++) {
            int m = mi * 16 + quad * 4 + r;
            gmax[mi][r] = fmaxf(fmaxf(redbuf[0][m], redbuf[1][m]),
                                fmaxf(redbuf[2][m], redbuf[3][m]));
        }
    __syncthreads();  // protect redbuf reuse

    // 2) exp + sum  (exp values overwrite acc)
    float psum[2][4] = {};
    #pragma unroll
    for (int mi = 0; mi < 2; mi++)
        #pragma unroll
        for (int ki = 0; ki < 8; ki++) {
            floatx4 e;
            #pragma unroll
            for (int r = 0; r < 4; r++) {
                e[r] = __expf(2.f * acc[mi][ki][r] - cs[ki] - gmax[mi][r]);
                psum[mi][r] += e[r];
            }
            acc[mi][ki] = e;
        }
    #pragma unroll
    for (int off = 1; off < 16; off <<= 1)
        #pragma unroll
        for (int mi = 0; mi < 2; mi++)
            #pragma unroll
            for (int r = 0; r < 4; r++)
                psum[mi][r] += __shfl_xor(psum[mi][r], off);
    if (l15 == 0) {
        #pragma unroll
        for (int mi = 0; mi < 2; mi++)
            #pragma unroll
            for (int r = 0; r < 4; r++)
                redbuf[wave][mi * 16 + quad * 4 + r] = psum[mi][r];
    }
    __syncthreads();
    float ginv[2][4];
    #pragma unroll
    for (int mi = 0; mi < 2; mi++)
        #pragma unroll
        for (int r = 0; r < 4; r++) {
            int m = mi * 16 + quad * 4 + r;
            ginv[mi][r] = 1.f / (redbuf[0][m] + redbuf[1][m] + redbuf[2][m] + redbuf[3][m]);
        }

    // 3) scale + transposed store: St[b][k][n], n = gm0%1024 + mi*16 + quad*4 + r
    const int b = gm0 >> 10;
    const int n0 = gm0 & 1023;
    #pragma unroll
    for (int mi = 0; mi < 2; mi++)
        #pragma unroll
        for (int ki = 0; ki < 8; ki++) {
            half4 s4;
            #pragma unroll
            for (int r = 0; r < 4; r++)
                s4[r] = (_Float16)(acc[mi][ki][r] * ginv[mi][r]);
            int k = k0w + ki * 16 + l15;
            *(half4*)&St[((size_t)b * KK + k) * NN + n0 + mi * 16 + quad * 4] = s4;
        }
}

// ---------------------------------------------------------------------------
// Cast+transpose X (fp32 [b][n][d]) -> Xt (fp16 [b][d][n])
// ---------------------------------------------------------------------------
__global__ __launch_bounds__(256) void transpose_xt(const float* __restrict__ X,
                                                    _Float16* __restrict__ Xt) {
    const int n0 = blockIdx.x * 64;
    const int d0 = blockIdx.y * 32;
    const int b = blockIdx.z;
    __shared__ _Float16 Ls[64][40];
    const int t = threadIdx.x;
    const int r = t >> 2, c8 = (t & 3) * 8;
    const float* src = X + ((size_t)(b << 10) + n0 + r) * DD + d0 + c8;
    float4 f0 = *(const float4*)src;
    float4 f1 = *(const float4*)(src + 4);
    half8 h;
    h[0] = (_Float16)f0.x; h[1] = (_Float16)f0.y; h[2] = (_Float16)f0.z; h[3] = (_Float16)f0.w;
    h[4] = (_Float16)f1.x; h[5] = (_Float16)f1.y; h[6] = (_Float16)f1.z; h[7] = (_Float16)f1.w;
    *(half8*)&Ls[r][c8] = h;
    __syncthreads();
    const int dr = t >> 3;          // 0..31
    const int nc = (t & 7) * 8;     // 0..56
    half8 o;
    #pragma unroll
    for (int j = 0; j < 8; j++) o[j] = Ls[nc + j][dr];
    *(half8*)&Xt[((size_t)b * DD + d0 + dr) * NN + n0 + nc] = o;
}

// ---------------------------------------------------------------------------
// GEMM2 (MFMA fp16): out[b][k][d] = sum_n St[b][k][n] * Xt[b][d][n]
// ---------------------------------------------------------------------------
__global__ __launch_bounds__(256) void gemm2_mfma(const _Float16* __restrict__ St,
                                                  const _Float16* __restrict__ Xt,
                                                  float* __restrict__ out) {
    __shared__ _Float16 As[128][40];  // [k][n-chunk]
    __shared__ _Float16 Bs[128][40];  // [d][n-chunk]

    const int d0 = blockIdx.x * 128;
    const int k0 = blockIdx.y * 128;
    const int b = blockIdx.z;
    const int t = threadIdx.x;
    const int wave = t >> 6;
    const int lane = t & 63;
    const int wm = (wave >> 1) * 64;
    const int wn = (wave & 1) * 64;
    const int l15 = lane & 15;
    const int quad = lane >> 4;

    const int sr = t >> 1;
    const int sc = (t & 1) * 16;

    floatx4 acc[4][4] = {};

    const _Float16* arow = St + ((size_t)b * KK + k0 + sr) * NN + sc;
    const _Float16* brow = Xt + ((size_t)b * DD + d0 + sr) * NN + sc;

    for (int n0 = 0; n0 < NN; n0 += 32) {
        half8 aa = *(const half8*)(arow + n0);
        half8 ab = *(const half8*)(arow + n0 + 8);
        half8 ba = *(const half8*)(brow + n0);
        half8 bb2 = *(const half8*)(brow + n0 + 8);
        __syncthreads();
        *(half8*)&As[sr][sc] = aa;  *(half8*)&As[sr][sc + 8] = ab;
        *(half8*)&Bs[sr][sc] = ba;  *(half8*)&Bs[sr][sc + 8] = bb2;
        __syncthreads();
        half8 af[4], bf[4];
        #pragma unroll
        for (int i = 0; i < 4; i++) af[i] = *(half8*)&As[wm + i * 16 + l15][quad * 8];
        #pragma unroll
        for (int i = 0; i < 4; i++) bf[i] = *(half8*)&Bs[wn + i * 16 + l15][quad * 8];
        #pragma unroll
        for (int mi = 0; mi < 4; mi++)
            #pragma unroll
            for (int ni = 0; ni < 4; ni++)
                acc[mi][ni] = __builtin_amdgcn_mfma_f32_16x16x32_f16(af[mi], bf[ni], acc[mi][ni], 0, 0, 0);
    }

    #pragma unroll
    for (int ni = 0; ni < 4; ni++) {
        #pragma unroll
        for (int mi = 0; mi < 4; mi++) {
            int k = k0 + wm + mi * 16 + quad * 4;
            int d = d0 + wn + ni * 16 + l15;
            float* op = out + ((size_t)b * KK + k) * DD + d;
            floatx4 a = acc[mi][ni];
            op[0 * DD] = a[0];
            op[1 * DD] = a[1];
            op[2 * DD] = a[2];
            op[3 * DD] = a[3];
        }
    }
}

// ---------------------------------------------------------------------------
extern "C" void kernel_launch(void* const* d_in, const int* in_sizes, int n_in,
                              void* d_out, int out_size, void* d_ws, size_t ws_size,
                              hipStream_t stream) {
    const float* x  = (const float*)d_in[0];   // [B,N,D] fp32
    const float* cb = (const float*)d_in[1];   // [K,D] fp32
    float* out = (float*)d_out;                // [B,K,D] fp32

    char* ws = (char*)d_ws;
    float*    csq = (float*)ws;                                   // 4 KB
    _Float16* Cbh = (_Float16*)(ws + 4096);                       // 768 KB
    _Float16* Xt  = (_Float16*)(ws + 4096 + 786432);              // 48 MB [b][d][n]
    _Float16* St  = (_Float16*)(ws + 4096 + 786432 + 50331648);   // 32 MB [b][k][n]

    cast_f32_f16<<<(KK * DD / 8 + 255) / 256, 256, 0, stream>>>(cb, Cbh, KK * DD / 8);
    csq_kernel<<<KK, 256, 0, stream>>>(cb, csq);

    // fused logits + softmax -> St (fp16, transposed)
    fused_logits_softmax<<<MM / 32, 256, 0, stream>>>(x, Cbh, csq, St);

    // X -> Xt (fp16, [b][d][n])
    transpose_xt<<<dim3(NN / 64, DD / 32, BB), 256, 0, stream>>>(x, Xt);

    // aggregate
    gemm2_mfma<<<dim3(DD / 128, KK / 128, BB), 256, 0, stream>>>(St, Xt, out);
}

// Round 4
// 312.141 us; speedup vs baseline: 2.3769x; 1.0603x over previous
//
#include <hip/hip_runtime.h>
#include <math.h>

// Problem constants
#define BB 32
#define NN 1024
#define DD 768
#define KK 512
#define MM (BB * NN)  // 32768 token rows

typedef _Float16 half8 __attribute__((ext_vector_type(8)));
typedef _Float16 half4 __attribute__((ext_vector_type(4)));
typedef float floatx4 __attribute__((ext_vector_type(4)));

// async global(16B) -> LDS, per-lane dest = uniform base + lane*16
__device__ __forceinline__ void load_lds16(const void* g, void* l) {
    __builtin_amdgcn_global_load_lds(
        (const __attribute__((address_space(1))) unsigned int*)g,
        (__attribute__((address_space(3))) unsigned int*)l, 16, 0, 0);
}

// ---------------------------------------------------------------------------
// cast fp32 -> fp16 (codebook only)
// ---------------------------------------------------------------------------
__global__ __launch_bounds__(256) void cast_f32_f16(const float* __restrict__ src,
                                                    _Float16* __restrict__ dst,
                                                    int n8) {
    int i = blockIdx.x * 256 + threadIdx.x;
    if (i >= n8) return;
    float4 a = ((const float4*)src)[2 * i];
    float4 b = ((const float4*)src)[2 * i + 1];
    half8 h;
    h[0] = (_Float16)a.x; h[1] = (_Float16)a.y; h[2] = (_Float16)a.z; h[3] = (_Float16)a.w;
    h[4] = (_Float16)b.x; h[5] = (_Float16)b.y; h[6] = (_Float16)b.z; h[7] = (_Float16)b.w;
    ((half8*)dst)[i] = h;
}

// ---------------------------------------------------------------------------
// csq[k] = sum_d codebook[k][d]^2
// ---------------------------------------------------------------------------
__global__ __launch_bounds__(256) void csq_kernel(const float* __restrict__ cb,
                                                  float* __restrict__ csq) {
    int k = blockIdx.x;
    const float* row = cb + (size_t)k * DD;
    float s = 0.f;
    for (int d = threadIdx.x; d < DD; d += 256) {
        float v = row[d];
        s += v * v;
    }
    #pragma unroll
    for (int off = 32; off > 0; off >>= 1) s += __shfl_down(s, off);
    __shared__ float sm[4];
    int lane = threadIdx.x & 63, wid = threadIdx.x >> 6;
    if (lane == 0) sm[wid] = s;
    __syncthreads();
    if (threadIdx.x == 0) csq[k] = sm[0] + sm[1] + sm[2] + sm[3];
}

// ---------------------------------------------------------------------------
// FUSED v2: logits (MFMA fp16) + softmax + transposed St write.
// Block = 512 threads (8 waves) = 64 tokens x all 512 k.
// Wave w: m-half wm=(w&1)*32, k-slab wk=(w>>1)*128. Acc 2x8 tiles (64 VGPR).
// Codebook chunk staged via global_load_lds into unpadded Cs[512][32].
// X chunk (fp32) staged via VGPR roundtrip + convert, prefetched 1 iter ahead.
// ---------------------------------------------------------------------------
__global__ __launch_bounds__(512) void fused_logits_softmax(
    const float* __restrict__ X,        // [M, D] fp32
    const _Float16* __restrict__ Cbh,   // [K, D] fp16
    const float* __restrict__ csq,      // [K]
    _Float16* __restrict__ St)          // [B, K, N] fp16
{
    __shared__ _Float16 Cs[512][32];    // 32 KB, unpadded (lds-dma layout)
    __shared__ _Float16 Xs[64][32];     // 4 KB
    __shared__ float redbuf[8][32];

    const int t = threadIdx.x;
    const int w = t >> 6;
    const int lane = t & 63;
    const int l15 = lane & 15;
    const int quad = lane >> 4;
    const int wm = (w & 1) * 32;        // token half within block
    const int wk = (w >> 1) * 128;      // k slab
    const int gm0 = blockIdx.x * 64;    // global token base

    float cs[8];
    #pragma unroll
    for (int ki = 0; ki < 8; ki++) cs[ki] = csq[wk + ki * 16 + l15];

    floatx4 acc[2][8] = {};

    // X staging geometry (fp32 -> fp16 roundtrip): 64 rows x 32 d
    const int xr = t >> 3;              // 0..63
    const int xc = (t & 7) * 4;         // 0..28
    const float* xsrc = X + (size_t)(gm0 + xr) * DD + xc;
    float4 xv = *(const float4*)xsrc;

    for (int d0 = 0; d0 < DD; d0 += 32) {
        __syncthreads();  // previous chunk's reads complete
        // async codebook chunk: 32 KB = 4 calls x 512 lanes x 16B
        #pragma unroll
        for (int c = 0; c < 4; c++) {
            int u = c * 512 + t;                 // 16B unit index
            int r = u >> 2, c8 = (u & 3) * 8;
            load_lds16(Cbh + (size_t)r * DD + d0 + c8, (_Float16*)Cs + u * 8);
        }
        // X chunk: convert + LDS write; prefetch next chunk
        half4 xh;
        xh[0] = (_Float16)xv.x; xh[1] = (_Float16)xv.y;
        xh[2] = (_Float16)xv.z; xh[3] = (_Float16)xv.w;
        *(half4*)&Xs[xr][xc] = xh;
        if (d0 + 32 < DD) xv = *(const float4*)(xsrc + d0 + 32);
        __syncthreads();  // drains lds-dma (vmcnt) + lgkm

        half8 af[2], bf[8];
        #pragma unroll
        for (int mi = 0; mi < 2; mi++) af[mi] = *(half8*)&Xs[wm + mi * 16 + l15][quad * 8];
        #pragma unroll
        for (int ki = 0; ki < 8; ki++) bf[ki] = *(half8*)&Cs[wk + ki * 16 + l15][quad * 8];
        #pragma unroll
        for (int mi = 0; mi < 2; mi++)
            #pragma unroll
            for (int ki = 0; ki < 8; ki++)
                acc[mi][ki] = __builtin_amdgcn_mfma_f32_16x16x32_f16(af[mi], bf[ki], acc[mi][ki], 0, 0, 0);
    }

    // ---- softmax over k=512 ----
    // logit = 2*acc - cs;  C/D layout: k = wk + ki*16 + l15, m-local = wm + mi*16 + quad*4 + r
    float pmax[2][4];
    #pragma unroll
    for (int mi = 0; mi < 2; mi++)
        #pragma unroll
        for (int r = 0; r < 4; r++) {
            float m = -1e30f;
            #pragma unroll
            for (int ki = 0; ki < 8; ki++)
                m = fmaxf(m, 2.f * acc[mi][ki][r] - cs[ki]);
            pmax[mi][r] = m;
        }
    #pragma unroll
    for (int off = 1; off < 16; off <<= 1)
        #pragma unroll
        for (int mi = 0; mi < 2; mi++)
            #pragma unroll
            for (int r = 0; r < 4; r++)
                pmax[mi][r] = fmaxf(pmax[mi][r], __shfl_xor(pmax[mi][r], off));
    __syncthreads();  // make sure last MFMA-loop LDS reads done before redbuf alias? (redbuf separate; protects nothing but cheap)
    if (l15 == 0) {
        #pragma unroll
        for (int mi = 0; mi < 2; mi++)
            #pragma unroll
            for (int r = 0; r < 4; r++)
                redbuf[w][mi * 16 + quad * 4 + r] = pmax[mi][r];
    }
    __syncthreads();
    float gmax[2][4];
    #pragma unroll
    for (int mi = 0; mi < 2; mi++)
        #pragma unroll
        for (int r = 0; r < 4; r++) {
            int idx = mi * 16 + quad * 4 + r;
            int wb = w & 1;
            gmax[mi][r] = fmaxf(fmaxf(redbuf[wb][idx], redbuf[wb + 2][idx]),
                                fmaxf(redbuf[wb + 4][idx], redbuf[wb + 6][idx]));
        }
    __syncthreads();  // redbuf reuse

    float psum[2][4] = {};
    #pragma unroll
    for (int mi = 0; mi < 2; mi++)
        #pragma unroll
        for (int ki = 0; ki < 8; ki++) {
            floatx4 e;
            #pragma unroll
            for (int r = 0; r < 4; r++) {
                e[r] = __expf(2.f * acc[mi][ki][r] - cs[ki] - gmax[mi][r]);
                psum[mi][r] += e[r];
            }
            acc[mi][ki] = e;
        }
    #pragma unroll
    for (int off = 1; off < 16; off <<= 1)
        #pragma unroll
        for (int mi = 0; mi < 2; mi++)
            #pragma unroll
            for (int r = 0; r < 4; r++)
                psum[mi][r] += __shfl_xor(psum[mi][r], off);
    if (l15 == 0) {
        #pragma unroll
        for (int mi = 0; mi < 2; mi++)
            #pragma unroll
            for (int r = 0; r < 4; r++)
                redbuf[w][mi * 16 + quad * 4 + r] = psum[mi][r];
    }
    __syncthreads();
    float ginv[2][4];
    #pragma unroll
    for (int mi = 0; mi < 2; mi++)
        #pragma unroll
        for (int r = 0; r < 4; r++) {
            int idx = mi * 16 + quad * 4 + r;
            int wb = w & 1;
            ginv[mi][r] = 1.f / (redbuf[wb][idx] + redbuf[wb + 2][idx] +
                                 redbuf[wb + 4][idx] + redbuf[wb + 6][idx]);
        }

    // scale + transposed store: St[b][k][n]
    const int b = gm0 >> 10;
    const int n0 = (gm0 & 1023) + wm;
    #pragma unroll
    for (int mi = 0; mi < 2; mi++)
        #pragma unroll
        for (int ki = 0; ki < 8; ki++) {
            half4 s4;
            #pragma unroll
            for (int r = 0; r < 4; r++)
                s4[r] = (_Float16)(acc[mi][ki][r] * ginv[mi][r]);
            int k = wk + ki * 16 + l15;
            *(half4*)&St[((size_t)b * KK + k) * NN + n0 + mi * 16 + quad * 4] = s4;
        }
}

// ---------------------------------------------------------------------------
// Cast+transpose X (fp32 [b][n][d]) -> Xt (fp16 [b][d][n])
// ---------------------------------------------------------------------------
__global__ __launch_bounds__(256) void transpose_xt(const float* __restrict__ X,
                                                    _Float16* __restrict__ Xt) {
    const int n0 = blockIdx.x * 64;
    const int d0 = blockIdx.y * 32;
    const int b = blockIdx.z;
    __shared__ _Float16 Ls[64][40];
    const int t = threadIdx.x;
    const int r = t >> 2, c8 = (t & 3) * 8;
    const float* src = X + ((size_t)(b << 10) + n0 + r) * DD + d0 + c8;
    float4 f0 = *(const float4*)src;
    float4 f1 = *(const float4*)(src + 4);
    half8 h;
    h[0] = (_Float16)f0.x; h[1] = (_Float16)f0.y; h[2] = (_Float16)f0.z; h[3] = (_Float16)f0.w;
    h[4] = (_Float16)f1.x; h[5] = (_Float16)f1.y; h[6] = (_Float16)f1.z; h[7] = (_Float16)f1.w;
    *(half8*)&Ls[r][c8] = h;
    __syncthreads();
    const int dr = t >> 3;          // 0..31
    const int nc = (t & 7) * 8;     // 0..56
    half8 o;
    #pragma unroll
    for (int j = 0; j < 8; j++) o[j] = Ls[nc + j][dr];
    *(half8*)&Xt[((size_t)b * DD + d0 + dr) * NN + n0 + nc] = o;
}

// ---------------------------------------------------------------------------
// GEMM2 v2 (m97-style): out[b][k][d] = sum_n St[b][k][n] * Xt[b][d][n]
// 128x128 tile, BK=32, unpadded LDS, global_load_lds staging.
// ---------------------------------------------------------------------------
__global__ __launch_bounds__(256) void gemm2_mfma(const _Float16* __restrict__ St,
                                                  const _Float16* __restrict__ Xt,
                                                  float* __restrict__ out) {
    __shared__ _Float16 As[128][32];  // [k][n-chunk] 8 KB
    __shared__ _Float16 Bs[128][32];  // [d][n-chunk] 8 KB

    const int d0 = blockIdx.x * 128;
    const int k0 = blockIdx.y * 128;
    const int b = blockIdx.z;
    const int t = threadIdx.x;
    const int wave = t >> 6;
    const int lane = t & 63;
    const int wm = (wave >> 1) * 64;
    const int wn = (wave & 1) * 64;
    const int l15 = lane & 15;
    const int quad = lane >> 4;

    floatx4 acc[4][4] = {};

    const _Float16* Abase = St + ((size_t)b * KK + k0) * NN;
    const _Float16* Bbase = Xt + ((size_t)b * DD + d0) * NN;

    for (int n0 = 0; n0 < NN; n0 += 32) {
        __syncthreads();
        #pragma unroll
        for (int c = 0; c < 2; c++) {
            int u = c * 256 + t;                 // 16B unit index, 0..511
            int r = u >> 2, c8 = (u & 3) * 8;
            load_lds16(Abase + (size_t)r * NN + n0 + c8, (_Float16*)As + u * 8);
            load_lds16(Bbase + (size_t)r * NN + n0 + c8, (_Float16*)Bs + u * 8);
        }
        __syncthreads();
        half8 af[4], bf[4];
        #pragma unroll
        for (int i = 0; i < 4; i++) af[i] = *(half8*)&As[wm + i * 16 + l15][quad * 8];
        #pragma unroll
        for (int i = 0; i < 4; i++) bf[i] = *(half8*)&Bs[wn + i * 16 + l15][quad * 8];
        #pragma unroll
        for (int mi = 0; mi < 4; mi++)
            #pragma unroll
            for (int ni = 0; ni < 4; ni++)
                acc[mi][ni] = __builtin_amdgcn_mfma_f32_16x16x32_f16(af[mi], bf[ni], acc[mi][ni], 0, 0, 0);
    }

    #pragma unroll
    for (int ni = 0; ni < 4; ni++) {
        #pragma unroll
        for (int mi = 0; mi < 4; mi++) {
            int k = k0 + wm + mi * 16 + quad * 4;
            int d = d0 + wn + ni * 16 + l15;
            float* op = out + ((size_t)b * KK + k) * DD + d;
            floatx4 a = acc[mi][ni];
            op[0 * DD] = a[0];
            op[1 * DD] = a[1];
            op[2 * DD] = a[2];
            op[3 * DD] = a[3];
        }
    }
}

// ---------------------------------------------------------------------------
extern "C" void kernel_launch(void* const* d_in, const int* in_sizes, int n_in,
                              void* d_out, int out_size, void* d_ws, size_t ws_size,
                              hipStream_t stream) {
    const float* x  = (const float*)d_in[0];   // [B,N,D] fp32
    const float* cb = (const float*)d_in[1];   // [K,D] fp32
    float* out = (float*)d_out;                // [B,K,D] fp32

    char* ws = (char*)d_ws;
    float*    csq = (float*)ws;                                   // 4 KB
    _Float16* Cbh = (_Float16*)(ws + 4096);                       // 768 KB
    _Float16* Xt  = (_Float16*)(ws + 4096 + 786432);              // 48 MB [b][d][n]
    _Float16* St  = (_Float16*)(ws + 4096 + 786432 + 50331648);   // 32 MB [b][k][n]

    cast_f32_f16<<<(KK * DD / 8 + 255) / 256, 256, 0, stream>>>(cb, Cbh, KK * DD / 8);
    csq_kernel<<<KK, 256, 0, stream>>>(cb, csq);

    // fused logits + softmax -> St (fp16, [b][k][n])
    fused_logits_softmax<<<MM / 64, 512, 0, stream>>>(x, Cbh, csq, St);

    // X -> Xt (fp16, [b][d][n])
    transpose_xt<<<dim3(NN / 64, DD / 32, BB), 256, 0, stream>>>(x, Xt);

    // aggregate
    gemm2_mfma<<<dim3(DD / 128, KK / 128, BB), 256, 0, stream>>>(St, Xt, out);
}